// Round 13
// baseline (401.303 us; speedup 1.0000x reference)
//
#include <hip/hip_runtime.h>

#define D 4096
#define RANK 1024
#define UELEMS 4194304ULL   // D*RANK
#define NTOT 16777216ULL    // 4^12 = D*D
#define QSCALE 16000.0f

typedef __attribute__((ext_vector_type(4))) int i32x4;

__device__ float g_tr[1];      // trace accumulator (zeroed by convert_w)
__device__ float g_scale[D];
__device__ float g_mdre[16];   // M-dagger tables: M†[s][i][j] = conj(M[s][j][i])
__device__ float g_mdim[16];

static __device__ __forceinline__ void load_lds16(const void* g, void* l) {
    __builtin_amdgcn_global_load_lds(
        (const __attribute__((address_space(1))) unsigned int*)g,
        (__attribute__((address_space(3))) unsigned int*)l, 16, 0, 0);
}

#define MFMA_I8 __builtin_amdgcn_mfma_i32_16x16x64_i8

// ---------------------------------------------------------------------------
// i8 split quantization of W = [Ur | Ui] with per-row scale (verified r6).
// Zeroes the trace accumulator (trace_inv kernel removed).
// ---------------------------------------------------------------------------
__global__ __launch_bounds__(256) void convert_w_i8(const float* __restrict__ P,
                                                    const float* __restrict__ Mre,
                                                    const float* __restrict__ Mim,
                                                    char* __restrict__ Wh,
                                                    char* __restrict__ Wl)
{
    if (blockIdx.x == 0 && threadIdx.x < 16) {
        const int s = threadIdx.x >> 2, i = (threadIdx.x >> 1) & 1, j = threadIdx.x & 1;
        g_mdre[threadIdx.x] =  Mre[s * 4 + j * 2 + i];
        g_mdim[threadIdx.x] = -Mim[s * 4 + j * 2 + i];
        if (threadIdx.x == 0) g_tr[0] = 0.f;
    }

    const int w = threadIdx.x >> 6, lane = threadIdx.x & 63;
    const int row = blockIdx.x * 4 + w;

    float ur[16], ui[16];
    const float* pr = P + (size_t)row * RANK + lane * 16;
    const float* pi = P + UELEMS + (size_t)row * RANK + lane * 16;
    #pragma unroll
    for (int q = 0; q < 4; ++q) {
        const float4 a = ((const float4*)pr)[q];
        const float4 b = ((const float4*)pi)[q];
        ur[q * 4 + 0] = a.x; ur[q * 4 + 1] = a.y; ur[q * 4 + 2] = a.z; ur[q * 4 + 3] = a.w;
        ui[q * 4 + 0] = b.x; ui[q * 4 + 1] = b.y; ui[q * 4 + 2] = b.z; ui[q * 4 + 3] = b.w;
    }
    float mx = 0.f;
    #pragma unroll
    for (int e = 0; e < 16; ++e)
        mx = fmaxf(mx, fmaxf(fabsf(ur[e]), fabsf(ui[e])));
    #pragma unroll
    for (int off = 1; off < 64; off <<= 1)
        mx = fmaxf(mx, __shfl_xor(mx, off));
    const float inv = mx > 0.f ? QSCALE / mx : 0.f;
    if (lane == 0) g_scale[row] = mx / QSCALE;

    int hr[16], lr[16], hi[16], li[16];
    #pragma unroll
    for (int e = 0; e < 16; ++e) {
        float q = ur[e] * inv;
        float hf = rintf(q * 0.0078125f);
        hr[e] = (int)hf; lr[e] = (int)rintf(q - 128.f * hf);
        q = ui[e] * inv;
        hf = rintf(q * 0.0078125f);
        hi[e] = (int)hf; li[e] = (int)rintf(q - 128.f * hf);
    }
    uint4 phr, plr, phi, pli;
    unsigned* dst[4] = {(unsigned*)&phr, (unsigned*)&plr, (unsigned*)&phi, (unsigned*)&pli};
    #pragma unroll
    for (int q = 0; q < 4; ++q) {
        unsigned a = 0, b = 0, c = 0, d = 0;
        #pragma unroll
        for (int k = 0; k < 4; ++k) {
            const int sh = k * 8;
            a |= (unsigned)(hr[q * 4 + k] & 255) << sh;
            b |= (unsigned)(lr[q * 4 + k] & 255) << sh;
            c |= (unsigned)(hi[q * 4 + k] & 255) << sh;
            d |= (unsigned)(li[q * 4 + k] & 255) << sh;
        }
        dst[0][q] = a; dst[1][q] = b; dst[2][q] = c; dst[3][q] = d;
    }
    const size_t b1 = (size_t)row * 2048 + lane * 16;
    *(uint4*)&Wh[b1] = phr;          *(uint4*)&Wl[b1] = plr;
    *(uint4*)&Wh[b1 + 1024] = phi;   *(uint4*)&Wl[b1 + 1024] = pli;
}

// ---------------------------------------------------------------------------
// Fused Hermitian GEMM in i8 (r14+swizzle, verified 123 µs; plateaued —
// kept verbatim as control).
// ---------------------------------------------------------------------------
__global__ __launch_bounds__(256, 2) void gemm_rho_i8(const char* __restrict__ Wh,
                                                      const char* __restrict__ Wl,
                                                      float2* __restrict__ rho)
{
    __shared__ __align__(16) char sA[2][4][64 * 64];   // 32768 B
    __shared__ __align__(16) char sB[2][4][64 * 64];   // 32768 B

    const int g0 = blockIdx.x;
    const int g = (g0 & 7) * 260 + (g0 >> 3);

    int bi = (int)((sqrtf(8.f * (float)g + 1.f) - 1.f) * 0.5f);
    while (bi * (bi + 1) / 2 > g) --bi;
    while ((bi + 1) * (bi + 2) / 2 <= g) ++bi;
    const int bj = g - bi * (bi + 1) / 2;
    const int row0 = bi << 6, col0 = bj << 6;

    const int t = threadIdx.x;
    const int lane = t & 63, w = t >> 6;
    const int wr = w >> 1, wc = w & 1;          // 2x2 waves of 32x32

    const int ra = t >> 2;
    const int kca = (t & 3) ^ ((ra >> 1) & 3);  // xor-swizzled k-slot
    const size_t aoff = (size_t)(row0 + ra) * 2048 + kca * 16;
    const size_t boff = (size_t)(col0 + ra) * 2048 + kca * 16;
    const int ldso = t * 16;

    const int m = lane & 15, gq = lane >> 4;
    const int fko = (gq ^ ((m >> 1) & 3)) * 16;

    i32x4 rehh[2][2], remx[2][2], iphh[2][2], ipmx[2][2], iqhh[2][2], iqmx[2][2];
    #pragma unroll
    for (int i = 0; i < 2; ++i)
        #pragma unroll
        for (int j = 0; j < 2; ++j) {
            rehh[i][j] = (i32x4){0, 0, 0, 0}; remx[i][j] = (i32x4){0, 0, 0, 0};
            iphh[i][j] = (i32x4){0, 0, 0, 0}; ipmx[i][j] = (i32x4){0, 0, 0, 0};
            iqhh[i][j] = (i32x4){0, 0, 0, 0}; iqmx[i][j] = (i32x4){0, 0, 0, 0};
        }

    char* const sA0 = &sA[0][0][0];
    char* const sB0 = &sB[0][0][0];

    load_lds16(Wh + aoff,        sA0 + ldso);
    load_lds16(Wl + aoff,        sA0 + 4096  + ldso);
    load_lds16(Wh + aoff + 1024, sA0 + 8192  + ldso);
    load_lds16(Wl + aoff + 1024, sA0 + 12288 + ldso);
    load_lds16(Wh + boff,        sB0 + ldso);
    load_lds16(Wl + boff,        sB0 + 4096  + ldso);
    load_lds16(Wh + boff + 1024, sB0 + 8192  + ldso);
    load_lds16(Wl + boff + 1024, sB0 + 12288 + ldso);
    __syncthreads();

#define DO_MFMA_J(j)                                                          \
    _Pragma("unroll")                                                         \
    for (int i = 0; i < 2; ++i) {                                             \
        i32x4 r;                                                              \
        r = rehh[i][j];                                                       \
        r = MFMA_I8(fa1h[i], b1h[j], r, 0, 0, 0);                             \
        r = MFMA_I8(fa2h[i], b2h[j], r, 0, 0, 0);                             \
        rehh[i][j] = r;                                                       \
        r = remx[i][j];                                                       \
        r = MFMA_I8(fa1h[i], b1l[j], r, 0, 0, 0);                             \
        r = MFMA_I8(fa1l[i], b1h[j], r, 0, 0, 0);                             \
        r = MFMA_I8(fa2h[i], b2l[j], r, 0, 0, 0);                             \
        r = MFMA_I8(fa2l[i], b2h[j], r, 0, 0, 0);                             \
        remx[i][j] = r;                                                       \
        r = MFMA_I8(fa2h[i], b1h[j], iphh[i][j], 0, 0, 0); iphh[i][j] = r;    \
        r = ipmx[i][j];                                                       \
        r = MFMA_I8(fa2h[i], b1l[j], r, 0, 0, 0);                             \
        r = MFMA_I8(fa2l[i], b1h[j], r, 0, 0, 0);                             \
        ipmx[i][j] = r;                                                       \
        r = MFMA_I8(fa1h[i], b2h[j], iqhh[i][j], 0, 0, 0); iqhh[i][j] = r;    \
        r = iqmx[i][j];                                                       \
        r = MFMA_I8(fa1h[i], b2l[j], r, 0, 0, 0);                             \
        r = MFMA_I8(fa1l[i], b2h[j], r, 0, 0, 0);                             \
        iqmx[i][j] = r;                                                       \
    }

    #pragma unroll 2
    for (int kt = 0; kt < 16; ++kt) {
        const int cur = kt & 1;
        const char* sAc = sA0 + cur * 16384;
        const char* sBc = sB0 + cur * 16384;
        char* sAn = sA0 + (cur ^ 1) * 16384;
        char* sBn = sB0 + (cur ^ 1) * 16384;
        const size_t ko = (size_t)(kt + 1) * 64;

        if (kt < 15) {
            load_lds16(Wh + aoff + ko,        sAn + ldso);
            load_lds16(Wl + aoff + ko,        sAn + 4096  + ldso);
            load_lds16(Wh + aoff + ko + 1024, sAn + 8192  + ldso);
            load_lds16(Wl + aoff + ko + 1024, sAn + 12288 + ldso);
            load_lds16(Wh + boff + ko,        sBn + ldso);
            load_lds16(Wl + boff + ko,        sBn + 4096  + ldso);
            load_lds16(Wh + boff + ko + 1024, sBn + 8192  + ldso);
            load_lds16(Wl + boff + ko + 1024, sBn + 12288 + ldso);
        }

        i32x4 fa1h[2], fa1l[2], fa2h[2], fa2l[2];
        i32x4 b1h[2], b1l[2], b2h[2], b2l[2];
        #pragma unroll
        for (int i = 0; i < 2; ++i) {
            const int off = (wr * 32 + i * 16 + m) * 64 + fko;
            fa1h[i] = *(const i32x4*)(sAc + off);
            fa1l[i] = *(const i32x4*)(sAc + 4096  + off);
            fa2h[i] = *(const i32x4*)(sAc + 8192  + off);
            fa2l[i] = *(const i32x4*)(sAc + 12288 + off);
        }
        #pragma unroll
        for (int j = 0; j < 2; ++j) {
            const int off = (wc * 32 + j * 16 + m) * 64 + fko;
            b1h[j] = *(const i32x4*)(sBc + off);
            b1l[j] = *(const i32x4*)(sBc + 4096  + off);
            b2h[j] = *(const i32x4*)(sBc + 8192  + off);
            b2l[j] = *(const i32x4*)(sBc + 12288 + off);
        }

        __builtin_amdgcn_s_setprio(1);
        DO_MFMA_J(0)
        DO_MFMA_J(1)
        __builtin_amdgcn_s_setprio(0);

        __syncthreads();
    }
#undef DO_MFMA_J

    #pragma unroll
    for (int j = 0; j < 2; ++j) {
        const int col = col0 + wc * 32 + j * 16 + m;
        const float sc = g_scale[col];
        const int c64 = col >> 6;
        #pragma unroll
        for (int i = 0; i < 2; ++i) {
            #pragma unroll
            for (int r = 0; r < 4; ++r) {
                const int row = row0 + wr * 32 + i * 16 + gq * 4 + r;
                const float s2 = g_scale[row] * sc;
                const float re = s2 * (16384.f * (float)rehh[i][j][r] + 128.f * (float)remx[i][j][r]);
                const float im = s2 * (16384.f * (float)(iphh[i][j][r] - iqhh[i][j][r])
                                      + 128.f * (float)(ipmx[i][j][r] - iqmx[i][j][r]));
                const int r64 = row >> 6;
                if (r64 > c64 || row >= col) rho[(size_t)row * D + col] = make_float2(re, im);
                if (r64 == c64 && row > col) rho[(size_t)col * D + row] = make_float2(re, -im);
            }
        }
    }
}

// ---------------------------------------------------------------------------
// 2-qubit staged contraction on a 4x4 register tile (verified r9).
// ---------------------------------------------------------------------------
static __device__ __forceinline__ void qmt2(float2* x,
                                            const float* __restrict__ Mre,
                                            const float* __restrict__ Mim)
{
    float2 y[16];
    #pragma unroll
    for (int sb = 0; sb < 4; ++sb)
        #pragma unroll
        for (int ja = 0; ja < 2; ++ja)
            #pragma unroll
            for (int ia = 0; ia < 2; ++ia) {
                float2 acc = make_float2(0.f, 0.f);
                #pragma unroll
                for (int ib = 0; ib < 2; ++ib)
                    #pragma unroll
                    for (int jb = 0; jb < 2; ++jb) {
                        const float mr = Mre[sb * 4 + ib * 2 + jb];
                        const float mi = Mim[sb * 4 + ib * 2 + jb];
                        const float2 v = x[(ja * 2 + jb) * 4 + ia * 2 + ib];
                        acc.x += mr * v.x - mi * v.y;
                        acc.y += mr * v.y + mi * v.x;
                    }
                y[sb * 4 + ja * 2 + ia] = acc;
            }
    #pragma unroll
    for (int sa = 0; sa < 4; ++sa)
        #pragma unroll
        for (int sb = 0; sb < 4; ++sb) {
            float2 acc = make_float2(0.f, 0.f);
            #pragma unroll
            for (int ia = 0; ia < 2; ++ia)
                #pragma unroll
                for (int ja = 0; ja < 2; ++ja) {
                    const float mr = Mre[sa * 4 + ia * 2 + ja];
                    const float mi = Mim[sa * 4 + ia * 2 + ja];
                    const float2 v = y[sb * 4 + ja * 2 + ia];
                    acc.x += mr * v.x - mi * v.y;
                    acc.y += mr * v.y + mi * v.x;
                }
            x[sa * 4 + sb] = acc;
        }
}

// ---------------------------------------------------------------------------
// The 3-stage 6-qubit pipeline (2 LDS exchanges), verified in pAh/p34.
// Input: x[j2*4+i2] = T[row = a4*4+j2][col = t4*4+i2], t=(a4<<4)|t4.
// Output: x[dd] = outcome (dd*256 + t). Caller syncs before reusing X.
// NOTE (r22): __syncthreads here may sync MORE than 256 threads — all
// callers must invoke the pipeline unconditionally and in lockstep.
// ---------------------------------------------------------------------------
static __device__ __forceinline__ void pA_pipeline(float2* x, float2* X, const int t,
                                                   const float* __restrict__ mre,
                                                   const float* __restrict__ mim)
{
    qmt2(x, mre, mim);
    #pragma unroll
    for (int d = 0; d < 16; ++d) X[t * 17 + d] = x[d];
    __syncthreads();
    const int a2 = t >> 6, t2 = (t >> 4) & 3, d1 = t & 15;
    #pragma unroll
    for (int j2 = 0; j2 < 4; ++j2)
        #pragma unroll
        for (int i2 = 0; i2 < 4; ++i2)
            x[j2 * 4 + i2] = X[((a2 * 4 + j2) * 16 + t2 * 4 + i2) * 17 + d1];
    __syncthreads();
    qmt2(x, mre, mim);
    #pragma unroll
    for (int d = 0; d < 16; ++d) X[(a2 * 4 + t2) * 257 + d * 16 + d1] = x[d];
    __syncthreads();
    const int e2 = t >> 4, e1 = t & 15;
    #pragma unroll
    for (int j2 = 0; j2 < 4; ++j2)
        #pragma unroll
        for (int i2 = 0; i2 < 4; ++i2)
            x[j2 * 4 + i2] = X[(j2 * 4 + i2) * 257 + e2 * 16 + e1];
    qmt2(x, mre, mim);
}

// ---------------------------------------------------------------------------
// Fused pass A, Hermitian. r22: 512-thread blocks run BOTH passes
// CONCURRENTLY — half h=0 computes the M pipeline (tile (rr,cc) slot), half
// h=1 the M† pipeline (mirror slot (cc,rr), conjugated). The two halves
// execute structurally identical code, so the pipeline's __syncthreads
// barriers align across the whole block. Eliminates x0[16] (32 VGPRs, the
// round-12 occupancy cap) and the serial second pipeline. Both halves read
// the same tile (second read L1/L2-hot). Diagonal tiles: h=1 computes but
// discards (keeps barriers convergent). LDS 2x34816 = 69632 B -> 2 blocks/CU
// (16 waves, same as before but shorter critical path per block).
// Output layout [o_hi(256)][rc(4096)][o_lo(16)] (r19, verified).
// ---------------------------------------------------------------------------
__global__ __launch_bounds__(512) void qmt_pAh(const float2* __restrict__ in,
                                               float2* __restrict__ out,
                                               const float* __restrict__ Mre,
                                               const float* __restrict__ Mim)
{
    __shared__ __align__(16) float2 X[2][256 * 17];   // 69632 B
    const int t = threadIdx.x & 255;
    const int h = threadIdx.x >> 8;                   // 0 = M, 1 = M-dagger
    const int g = blockIdx.x;
    int rr = (int)((sqrtf(8.f * (float)g + 1.f) - 1.f) * 0.5f);
    while (rr * (rr + 1) / 2 > g) --rr;
    while ((rr + 1) * (rr + 2) / 2 <= g) ++rr;
    const int cc = g - rr * (rr + 1) / 2;             // cc <= rr

    const int a4 = t >> 4, t4 = t & 15;
    float2 x[16];
    #pragma unroll
    for (int j2 = 0; j2 < 4; ++j2) {
        const float2* p = in + ((size_t)(rr * 64 + a4 * 4 + j2)) * 4096 + cc * 64 + t4 * 4;
        const float4 v0 = ((const float4*)p)[0];
        const float4 v1 = ((const float4*)p)[1];
        x[j2 * 4 + 0] = make_float2(v0.x, v0.y);
        x[j2 * 4 + 1] = make_float2(v0.z, v0.w);
        x[j2 * 4 + 2] = make_float2(v1.x, v1.y);
        x[j2 * 4 + 3] = make_float2(v1.z, v1.w);
    }

    // trace contribution: diagonal tiles, h=0 threads holding diagonal entries
    if (h == 0 && rr == cc && a4 == t4)
        atomicAdd(&g_tr[0], x[0].x + x[5].x + x[10].x + x[15].x);

    // both halves run the pipeline unconditionally (barriers sync all 512)
    pA_pipeline(x, X[h], t,
                h ? (const float*)g_mdre : Mre,
                h ? (const float*)g_mdim : Mim);

    const size_t wbase = (size_t)(t >> 4) * 65536 + (t & 15);
    if (h == 0) {
        const size_t rc0 = (size_t)(rr * 64 + cc) * 16;
        #pragma unroll
        for (int d = 0; d < 16; ++d)
            out[(size_t)d * 1048576 + wbase + rc0] = x[d];
    } else if (rr != cc) {
        const size_t rc1 = (size_t)(cc * 64 + rr) * 16;
        #pragma unroll
        for (int d = 0; d < 16; ++d)
            out[(size_t)d * 1048576 + wbase + rc1] = make_float2(x[d].x, -x[d].y);
    }
}

// ---------------------------------------------------------------------------
// r19: fused pass B+C (verified round 10) — one 6-qubit contraction over
// (rr,cc) per LSB-outcome batch d34. Reads in[o_hi*65536 + rc*16 + o_lo];
// sibling blocks sharing o_hi are XCD-grouped via d34=(b&7)*512+(b>>3).
// Output out[d34*4096 + outcome] real. Gather pos = (idx&4095)*4096 +
// (idx>>12). Kept verbatim for attribution.
// ---------------------------------------------------------------------------
__global__ __launch_bounds__(256) void qmt_p34(const float2* __restrict__ in,
                                               float* __restrict__ out,
                                               const float* __restrict__ Mre,
                                               const float* __restrict__ Mim)
{
    __shared__ __align__(16) float2 X[256 * 17];   // 34816 B
    const int t = threadIdx.x;
    const int b = blockIdx.x;
    const int d34 = (b & 7) * 512 + (b >> 3);      // XCD-grouped batch
    const int ohi = d34 >> 4, olo = d34 & 15;

    const float2* base = in + (size_t)ohi * 65536 + olo;
    const int a4 = t >> 4, t4 = t & 15;
    float2 x[16];
    #pragma unroll
    for (int j2 = 0; j2 < 4; ++j2) {
        const int rcr = (a4 * 4 + j2) * 64 + t4 * 4;
        #pragma unroll
        for (int i2 = 0; i2 < 4; ++i2)
            x[j2 * 4 + i2] = base[(size_t)(rcr + i2) * 16];
    }

    pA_pipeline(x, X, t, Mre, Mim);

    const size_t ob = (size_t)d34 * 4096 + t;
    #pragma unroll
    for (int d = 0; d < 16; ++d)
        out[ob + (size_t)d * 256] = x[d].x;
}

// ---------------------------------------------------------------------------
__global__ void gather_idx(const float* __restrict__ P, const int* __restrict__ idxs,
                           float* __restrict__ out, const int n)
{
    const int i = blockIdx.x * 256 + threadIdx.x;
    if (i < n) {
        const int idx = idxs[i];
        const size_t pos = (size_t)(idx & 4095) * 4096 + (idx >> 12);
        out[i] = P[pos] * (1.0f / g_tr[0]);
    }
}

// ---------------------------------------------------------------------------
extern "C" void kernel_launch(void* const* d_in, const int* in_sizes, int n_in,
                              void* d_out, int out_size, void* d_ws, size_t ws_size,
                              hipStream_t stream)
{
    const float* params = (const float*)d_in[0];  // (2, D, RANK) fp32
    const float* Mre    = (const float*)d_in[1];
    const float* Mim    = (const float*)d_in[2];
    const int*   idxs   = (const int*)d_in[3];
    float*       out    = (float*)d_out;

    float* ws = (float*)d_ws;
    float2* A  = (float2*)ws;                 // 134 MB plane
    float2* Bp = (float2*)(ws + 2 * NTOT);    // 134 MB plane
    char* Wh = (char*)Bp;                     // dead after gemm
    char* Wl = Wh + (size_t)D * 2048;

    convert_w_i8<<<1024, 256, 0, stream>>>(params, Mre, Mim, Wh, Wl);
    gemm_rho_i8<<<2080, 256, 0, stream>>>(Wh, Wl, A);

    qmt_pAh<<<2080, 512, 0, stream>>>(A, Bp, Mre, Mim);  // 6 LSB qubits, dual-pass
    qmt_p34<<<4096, 256, 0, stream>>>(Bp, (float*)A, Mre, Mim);  // 6 MSB qubits

    gather_idx<<<(out_size + 255) / 256, 256, 0, stream>>>((float*)A, idxs, out, out_size);
}

// Round 14
// 361.755 us; speedup vs baseline: 1.1093x; 1.1093x over previous
//
#include <hip/hip_runtime.h>

#define D 4096
#define RANK 1024
#define UELEMS 4194304ULL   // D*RANK
#define NTOT 16777216ULL    // 4^12 = D*D
#define QSCALE 16000.0f

typedef __attribute__((ext_vector_type(4))) int i32x4;

__device__ float g_tr[1];      // trace accumulator (zeroed by convert_w)
__device__ float g_scale[D];
__device__ float g_mdre[16];   // M-dagger tables: M†[s][i][j] = conj(M[s][j][i])
__device__ float g_mdim[16];

static __device__ __forceinline__ void load_lds16(const void* g, void* l) {
    __builtin_amdgcn_global_load_lds(
        (const __attribute__((address_space(1))) unsigned int*)g,
        (__attribute__((address_space(3))) unsigned int*)l, 16, 0, 0);
}

#define MFMA_I8 __builtin_amdgcn_mfma_i32_16x16x64_i8

// ---------------------------------------------------------------------------
// i8 split quantization of W = [Ur | Ui] with per-row scale (verified r6).
// Zeroes the trace accumulator (trace_inv kernel removed).
// ---------------------------------------------------------------------------
__global__ __launch_bounds__(256) void convert_w_i8(const float* __restrict__ P,
                                                    const float* __restrict__ Mre,
                                                    const float* __restrict__ Mim,
                                                    char* __restrict__ Wh,
                                                    char* __restrict__ Wl)
{
    if (blockIdx.x == 0 && threadIdx.x < 16) {
        const int s = threadIdx.x >> 2, i = (threadIdx.x >> 1) & 1, j = threadIdx.x & 1;
        g_mdre[threadIdx.x] =  Mre[s * 4 + j * 2 + i];
        g_mdim[threadIdx.x] = -Mim[s * 4 + j * 2 + i];
        if (threadIdx.x == 0) g_tr[0] = 0.f;
    }

    const int w = threadIdx.x >> 6, lane = threadIdx.x & 63;
    const int row = blockIdx.x * 4 + w;

    float ur[16], ui[16];
    const float* pr = P + (size_t)row * RANK + lane * 16;
    const float* pi = P + UELEMS + (size_t)row * RANK + lane * 16;
    #pragma unroll
    for (int q = 0; q < 4; ++q) {
        const float4 a = ((const float4*)pr)[q];
        const float4 b = ((const float4*)pi)[q];
        ur[q * 4 + 0] = a.x; ur[q * 4 + 1] = a.y; ur[q * 4 + 2] = a.z; ur[q * 4 + 3] = a.w;
        ui[q * 4 + 0] = b.x; ui[q * 4 + 1] = b.y; ui[q * 4 + 2] = b.z; ui[q * 4 + 3] = b.w;
    }
    float mx = 0.f;
    #pragma unroll
    for (int e = 0; e < 16; ++e)
        mx = fmaxf(mx, fmaxf(fabsf(ur[e]), fabsf(ui[e])));
    #pragma unroll
    for (int off = 1; off < 64; off <<= 1)
        mx = fmaxf(mx, __shfl_xor(mx, off));
    const float inv = mx > 0.f ? QSCALE / mx : 0.f;
    if (lane == 0) g_scale[row] = mx / QSCALE;

    int hr[16], lr[16], hi[16], li[16];
    #pragma unroll
    for (int e = 0; e < 16; ++e) {
        float q = ur[e] * inv;
        float hf = rintf(q * 0.0078125f);
        hr[e] = (int)hf; lr[e] = (int)rintf(q - 128.f * hf);
        q = ui[e] * inv;
        hf = rintf(q * 0.0078125f);
        hi[e] = (int)hf; li[e] = (int)rintf(q - 128.f * hf);
    }
    uint4 phr, plr, phi, pli;
    unsigned* dst[4] = {(unsigned*)&phr, (unsigned*)&plr, (unsigned*)&phi, (unsigned*)&pli};
    #pragma unroll
    for (int q = 0; q < 4; ++q) {
        unsigned a = 0, b = 0, c = 0, d = 0;
        #pragma unroll
        for (int k = 0; k < 4; ++k) {
            const int sh = k * 8;
            a |= (unsigned)(hr[q * 4 + k] & 255) << sh;
            b |= (unsigned)(lr[q * 4 + k] & 255) << sh;
            c |= (unsigned)(hi[q * 4 + k] & 255) << sh;
            d |= (unsigned)(li[q * 4 + k] & 255) << sh;
        }
        dst[0][q] = a; dst[1][q] = b; dst[2][q] = c; dst[3][q] = d;
    }
    const size_t b1 = (size_t)row * 2048 + lane * 16;
    *(uint4*)&Wh[b1] = phr;          *(uint4*)&Wl[b1] = plr;
    *(uint4*)&Wh[b1 + 1024] = phi;   *(uint4*)&Wl[b1 + 1024] = pli;
}

// ---------------------------------------------------------------------------
// Fused Hermitian GEMM in i8 (r14+swizzle, verified 122-123 µs; plateaued —
// 6-variant ledger brackets 123-141 -> kept verbatim).
// ---------------------------------------------------------------------------
__global__ __launch_bounds__(256, 2) void gemm_rho_i8(const char* __restrict__ Wh,
                                                      const char* __restrict__ Wl,
                                                      float2* __restrict__ rho)
{
    __shared__ __align__(16) char sA[2][4][64 * 64];   // 32768 B
    __shared__ __align__(16) char sB[2][4][64 * 64];   // 32768 B

    const int g0 = blockIdx.x;
    const int g = (g0 & 7) * 260 + (g0 >> 3);

    int bi = (int)((sqrtf(8.f * (float)g + 1.f) - 1.f) * 0.5f);
    while (bi * (bi + 1) / 2 > g) --bi;
    while ((bi + 1) * (bi + 2) / 2 <= g) ++bi;
    const int bj = g - bi * (bi + 1) / 2;
    const int row0 = bi << 6, col0 = bj << 6;

    const int t = threadIdx.x;
    const int lane = t & 63, w = t >> 6;
    const int wr = w >> 1, wc = w & 1;          // 2x2 waves of 32x32

    const int ra = t >> 2;
    const int kca = (t & 3) ^ ((ra >> 1) & 3);  // xor-swizzled k-slot
    const size_t aoff = (size_t)(row0 + ra) * 2048 + kca * 16;
    const size_t boff = (size_t)(col0 + ra) * 2048 + kca * 16;
    const int ldso = t * 16;

    const int m = lane & 15, gq = lane >> 4;
    const int fko = (gq ^ ((m >> 1) & 3)) * 16;

    i32x4 rehh[2][2], remx[2][2], iphh[2][2], ipmx[2][2], iqhh[2][2], iqmx[2][2];
    #pragma unroll
    for (int i = 0; i < 2; ++i)
        #pragma unroll
        for (int j = 0; j < 2; ++j) {
            rehh[i][j] = (i32x4){0, 0, 0, 0}; remx[i][j] = (i32x4){0, 0, 0, 0};
            iphh[i][j] = (i32x4){0, 0, 0, 0}; ipmx[i][j] = (i32x4){0, 0, 0, 0};
            iqhh[i][j] = (i32x4){0, 0, 0, 0}; iqmx[i][j] = (i32x4){0, 0, 0, 0};
        }

    char* const sA0 = &sA[0][0][0];
    char* const sB0 = &sB[0][0][0];

    load_lds16(Wh + aoff,        sA0 + ldso);
    load_lds16(Wl + aoff,        sA0 + 4096  + ldso);
    load_lds16(Wh + aoff + 1024, sA0 + 8192  + ldso);
    load_lds16(Wl + aoff + 1024, sA0 + 12288 + ldso);
    load_lds16(Wh + boff,        sB0 + ldso);
    load_lds16(Wl + boff,        sB0 + 4096  + ldso);
    load_lds16(Wh + boff + 1024, sB0 + 8192  + ldso);
    load_lds16(Wl + boff + 1024, sB0 + 12288 + ldso);
    __syncthreads();

#define DO_MFMA_J(j)                                                          \
    _Pragma("unroll")                                                         \
    for (int i = 0; i < 2; ++i) {                                             \
        i32x4 r;                                                              \
        r = rehh[i][j];                                                       \
        r = MFMA_I8(fa1h[i], b1h[j], r, 0, 0, 0);                             \
        r = MFMA_I8(fa2h[i], b2h[j], r, 0, 0, 0);                             \
        rehh[i][j] = r;                                                       \
        r = remx[i][j];                                                       \
        r = MFMA_I8(fa1h[i], b1l[j], r, 0, 0, 0);                             \
        r = MFMA_I8(fa1l[i], b1h[j], r, 0, 0, 0);                             \
        r = MFMA_I8(fa2h[i], b2l[j], r, 0, 0, 0);                             \
        r = MFMA_I8(fa2l[i], b2h[j], r, 0, 0, 0);                             \
        remx[i][j] = r;                                                       \
        r = MFMA_I8(fa2h[i], b1h[j], iphh[i][j], 0, 0, 0); iphh[i][j] = r;    \
        r = ipmx[i][j];                                                       \
        r = MFMA_I8(fa2h[i], b1l[j], r, 0, 0, 0);                             \
        r = MFMA_I8(fa2l[i], b1h[j], r, 0, 0, 0);                             \
        ipmx[i][j] = r;                                                       \
        r = MFMA_I8(fa1h[i], b2h[j], iqhh[i][j], 0, 0, 0); iqhh[i][j] = r;    \
        r = iqmx[i][j];                                                       \
        r = MFMA_I8(fa1h[i], b2l[j], r, 0, 0, 0);                             \
        r = MFMA_I8(fa1l[i], b2h[j], r, 0, 0, 0);                             \
        iqmx[i][j] = r;                                                       \
    }

    #pragma unroll 2
    for (int kt = 0; kt < 16; ++kt) {
        const int cur = kt & 1;
        const char* sAc = sA0 + cur * 16384;
        const char* sBc = sB0 + cur * 16384;
        char* sAn = sA0 + (cur ^ 1) * 16384;
        char* sBn = sB0 + (cur ^ 1) * 16384;
        const size_t ko = (size_t)(kt + 1) * 64;

        if (kt < 15) {
            load_lds16(Wh + aoff + ko,        sAn + ldso);
            load_lds16(Wl + aoff + ko,        sAn + 4096  + ldso);
            load_lds16(Wh + aoff + ko + 1024, sAn + 8192  + ldso);
            load_lds16(Wl + aoff + ko + 1024, sAn + 12288 + ldso);
            load_lds16(Wh + boff + ko,        sBn + ldso);
            load_lds16(Wl + boff + ko,        sBn + 4096  + ldso);
            load_lds16(Wh + boff + ko + 1024, sBn + 8192  + ldso);
            load_lds16(Wl + boff + ko + 1024, sBn + 12288 + ldso);
        }

        i32x4 fa1h[2], fa1l[2], fa2h[2], fa2l[2];
        i32x4 b1h[2], b1l[2], b2h[2], b2l[2];
        #pragma unroll
        for (int i = 0; i < 2; ++i) {
            const int off = (wr * 32 + i * 16 + m) * 64 + fko;
            fa1h[i] = *(const i32x4*)(sAc + off);
            fa1l[i] = *(const i32x4*)(sAc + 4096  + off);
            fa2h[i] = *(const i32x4*)(sAc + 8192  + off);
            fa2l[i] = *(const i32x4*)(sAc + 12288 + off);
        }
        #pragma unroll
        for (int j = 0; j < 2; ++j) {
            const int off = (wc * 32 + j * 16 + m) * 64 + fko;
            b1h[j] = *(const i32x4*)(sBc + off);
            b1l[j] = *(const i32x4*)(sBc + 4096  + off);
            b2h[j] = *(const i32x4*)(sBc + 8192  + off);
            b2l[j] = *(const i32x4*)(sBc + 12288 + off);
        }

        __builtin_amdgcn_s_setprio(1);
        DO_MFMA_J(0)
        DO_MFMA_J(1)
        __builtin_amdgcn_s_setprio(0);

        __syncthreads();
    }
#undef DO_MFMA_J

    #pragma unroll
    for (int j = 0; j < 2; ++j) {
        const int col = col0 + wc * 32 + j * 16 + m;
        const float sc = g_scale[col];
        const int c64 = col >> 6;
        #pragma unroll
        for (int i = 0; i < 2; ++i) {
            #pragma unroll
            for (int r = 0; r < 4; ++r) {
                const int row = row0 + wr * 32 + i * 16 + gq * 4 + r;
                const float s2 = g_scale[row] * sc;
                const float re = s2 * (16384.f * (float)rehh[i][j][r] + 128.f * (float)remx[i][j][r]);
                const float im = s2 * (16384.f * (float)(iphh[i][j][r] - iqhh[i][j][r])
                                      + 128.f * (float)(ipmx[i][j][r] - iqmx[i][j][r]));
                const int r64 = row >> 6;
                if (r64 > c64 || row >= col) rho[(size_t)row * D + col] = make_float2(re, im);
                if (r64 == c64 && row > col) rho[(size_t)col * D + row] = make_float2(re, -im);
            }
        }
    }
}

// ---------------------------------------------------------------------------
// 2-qubit staged contraction on a 4x4 register tile (verified r9).
// ---------------------------------------------------------------------------
static __device__ __forceinline__ void qmt2(float2* x,
                                            const float* __restrict__ Mre,
                                            const float* __restrict__ Mim)
{
    float2 y[16];
    #pragma unroll
    for (int sb = 0; sb < 4; ++sb)
        #pragma unroll
        for (int ja = 0; ja < 2; ++ja)
            #pragma unroll
            for (int ia = 0; ia < 2; ++ia) {
                float2 acc = make_float2(0.f, 0.f);
                #pragma unroll
                for (int ib = 0; ib < 2; ++ib)
                    #pragma unroll
                    for (int jb = 0; jb < 2; ++jb) {
                        const float mr = Mre[sb * 4 + ib * 2 + jb];
                        const float mi = Mim[sb * 4 + ib * 2 + jb];
                        const float2 v = x[(ja * 2 + jb) * 4 + ia * 2 + ib];
                        acc.x += mr * v.x - mi * v.y;
                        acc.y += mr * v.y + mi * v.x;
                    }
                y[sb * 4 + ja * 2 + ia] = acc;
            }
    #pragma unroll
    for (int sa = 0; sa < 4; ++sa)
        #pragma unroll
        for (int sb = 0; sb < 4; ++sb) {
            float2 acc = make_float2(0.f, 0.f);
            #pragma unroll
            for (int ia = 0; ia < 2; ++ia)
                #pragma unroll
                for (int ja = 0; ja < 2; ++ja) {
                    const float mr = Mre[sa * 4 + ia * 2 + ja];
                    const float mi = Mim[sa * 4 + ia * 2 + ja];
                    const float2 v = y[sb * 4 + ja * 2 + ia];
                    acc.x += mr * v.x - mi * v.y;
                    acc.y += mr * v.y + mi * v.x;
                }
            x[sa * 4 + sb] = acc;
        }
}

// ---------------------------------------------------------------------------
// The 3-stage 6-qubit pipeline (2 LDS exchanges), verified in pAh/p34.
// Input: x[j2*4+i2] = T[row = a4*4+j2][col = t4*4+i2], t=(a4<<4)|t4.
// Output: x[dd] = outcome (dd*256 + t). Caller syncs before reusing X.
// ---------------------------------------------------------------------------
static __device__ __forceinline__ void pA_pipeline(float2* x, float2* X, const int t,
                                                   const float* __restrict__ mre,
                                                   const float* __restrict__ mim)
{
    qmt2(x, mre, mim);
    #pragma unroll
    for (int d = 0; d < 16; ++d) X[t * 17 + d] = x[d];
    __syncthreads();
    const int a2 = t >> 6, t2 = (t >> 4) & 3, d1 = t & 15;
    #pragma unroll
    for (int j2 = 0; j2 < 4; ++j2)
        #pragma unroll
        for (int i2 = 0; i2 < 4; ++i2)
            x[j2 * 4 + i2] = X[((a2 * 4 + j2) * 16 + t2 * 4 + i2) * 17 + d1];
    __syncthreads();
    qmt2(x, mre, mim);
    #pragma unroll
    for (int d = 0; d < 16; ++d) X[(a2 * 4 + t2) * 257 + d * 16 + d1] = x[d];
    __syncthreads();
    const int e2 = t >> 4, e1 = t & 15;
    #pragma unroll
    for (int j2 = 0; j2 < 4; ++j2)
        #pragma unroll
        for (int i2 = 0; i2 < 4; ++i2)
            x[j2 * 4 + i2] = X[(j2 * 4 + i2) * 257 + e2 * 16 + e1];
    qmt2(x, mre, mim);
}

// ---------------------------------------------------------------------------
// Fused pass A, Hermitian — round-10/12 two-pass structure (verified best:
// one tile read, both passes serial in-block; pass-split regressed +19 µs,
// 512-thread dual-pass regressed +32 µs — barrier convoy). Diagonal blocks
// accumulate the rho trace (trace_inv removed).
// Output layout [o_hi(256)][rc(4096)][o_lo(16)] (r19, verified).
// ---------------------------------------------------------------------------
__global__ __launch_bounds__(256) void qmt_pAh(const float2* __restrict__ in,
                                               float2* __restrict__ out,
                                               const float* __restrict__ Mre,
                                               const float* __restrict__ Mim)
{
    __shared__ __align__(16) float2 X[256 * 17];   // 34816 B
    const int t = threadIdx.x;
    const int g = blockIdx.x;
    int rr = (int)((sqrtf(8.f * (float)g + 1.f) - 1.f) * 0.5f);
    while (rr * (rr + 1) / 2 > g) --rr;
    while ((rr + 1) * (rr + 2) / 2 <= g) ++rr;
    const int cc = g - rr * (rr + 1) / 2;          // cc <= rr

    const int a4 = t >> 4, t4 = t & 15;
    float2 x0[16], x[16];
    #pragma unroll
    for (int j2 = 0; j2 < 4; ++j2) {
        const float2* p = in + ((size_t)(rr * 64 + a4 * 4 + j2)) * 4096 + cc * 64 + t4 * 4;
        const float4 v0 = ((const float4*)p)[0];
        const float4 v1 = ((const float4*)p)[1];
        x0[j2 * 4 + 0] = make_float2(v0.x, v0.y);
        x0[j2 * 4 + 1] = make_float2(v0.z, v0.w);
        x0[j2 * 4 + 2] = make_float2(v1.x, v1.y);
        x0[j2 * 4 + 3] = make_float2(v1.z, v1.w);
    }

    // trace contribution: diagonal tiles, threads holding diagonal entries
    if (rr == cc && a4 == t4)
        atomicAdd(&g_tr[0], x0[0].x + x0[5].x + x0[10].x + x0[15].x);

    const size_t wbase = (size_t)(t >> 4) * 65536 + (t & 15);

    // pass 0: M, tile (rr,cc)
    #pragma unroll
    for (int q = 0; q < 16; ++q) x[q] = x0[q];
    pA_pipeline(x, X, t, Mre, Mim);
    {
        const size_t rc0 = (size_t)(rr * 64 + cc) * 16;
        #pragma unroll
        for (int d = 0; d < 16; ++d)
            out[(size_t)d * 1048576 + wbase + rc0] = x[d];
    }

    // pass 1: M-dagger + conjugate, tile (cc,rr)
    if (rr != cc) {
        __syncthreads();
        #pragma unroll
        for (int q = 0; q < 16; ++q) x[q] = x0[q];
        pA_pipeline(x, X, t, g_mdre, g_mdim);
        const size_t rc1 = (size_t)(cc * 64 + rr) * 16;
        #pragma unroll
        for (int d = 0; d < 16; ++d)
            out[(size_t)d * 1048576 + wbase + rc1] = make_float2(x[d].x, -x[d].y);
    }
}

// ---------------------------------------------------------------------------
// r19: fused pass B+C (verified) — one 6-qubit contraction over (rr,cc) per
// LSB-outcome batch d34. Reads in[o_hi*65536 + rc*16 + o_lo]; sibling blocks
// sharing o_hi are XCD-grouped via d34=(b&7)*512+(b>>3). Output
// out[d34*4096 + outcome] real. Gather pos = (idx&4095)*4096 + (idx>>12).
// ---------------------------------------------------------------------------
__global__ __launch_bounds__(256) void qmt_p34(const float2* __restrict__ in,
                                               float* __restrict__ out,
                                               const float* __restrict__ Mre,
                                               const float* __restrict__ Mim)
{
    __shared__ __align__(16) float2 X[256 * 17];   // 34816 B
    const int t = threadIdx.x;
    const int b = blockIdx.x;
    const int d34 = (b & 7) * 512 + (b >> 3);      // XCD-grouped batch
    const int ohi = d34 >> 4, olo = d34 & 15;

    const float2* base = in + (size_t)ohi * 65536 + olo;
    const int a4 = t >> 4, t4 = t & 15;
    float2 x[16];
    #pragma unroll
    for (int j2 = 0; j2 < 4; ++j2) {
        const int rcr = (a4 * 4 + j2) * 64 + t4 * 4;
        #pragma unroll
        for (int i2 = 0; i2 < 4; ++i2)
            x[j2 * 4 + i2] = base[(size_t)(rcr + i2) * 16];
    }

    pA_pipeline(x, X, t, Mre, Mim);

    const size_t ob = (size_t)d34 * 4096 + t;
    #pragma unroll
    for (int d = 0; d < 16; ++d)
        out[ob + (size_t)d * 256] = x[d].x;
}

// ---------------------------------------------------------------------------
__global__ void gather_idx(const float* __restrict__ P, const int* __restrict__ idxs,
                           float* __restrict__ out, const int n)
{
    const int i = blockIdx.x * 256 + threadIdx.x;
    if (i < n) {
        const int idx = idxs[i];
        const size_t pos = (size_t)(idx & 4095) * 4096 + (idx >> 12);
        out[i] = P[pos] * (1.0f / g_tr[0]);
    }
}

// ---------------------------------------------------------------------------
extern "C" void kernel_launch(void* const* d_in, const int* in_sizes, int n_in,
                              void* d_out, int out_size, void* d_ws, size_t ws_size,
                              hipStream_t stream)
{
    const float* params = (const float*)d_in[0];  // (2, D, RANK) fp32
    const float* Mre    = (const float*)d_in[1];
    const float* Mim    = (const float*)d_in[2];
    const int*   idxs   = (const int*)d_in[3];
    float*       out    = (float*)d_out;

    float* ws = (float*)d_ws;
    float2* A  = (float2*)ws;                 // 134 MB plane
    float2* Bp = (float2*)(ws + 2 * NTOT);    // 134 MB plane
    char* Wh = (char*)Bp;                     // dead after gemm
    char* Wl = Wh + (size_t)D * 2048;

    convert_w_i8<<<1024, 256, 0, stream>>>(params, Mre, Mim, Wh, Wl);
    gemm_rho_i8<<<2080, 256, 0, stream>>>(Wh, Wl, A);

    qmt_pAh<<<2080, 256, 0, stream>>>(A, Bp, Mre, Mim);  // 6 LSB qubits, two-pass
    qmt_p34<<<4096, 256, 0, stream>>>(Bp, (float*)A, Mre, Mim);  // 6 MSB qubits

    gather_idx<<<(out_size + 255) / 256, 256, 0, stream>>>((float*)A, idxs, out, out_size);
}